// Round 7
// baseline (192.653 us; speedup 1.0000x reference)
//
#include <hip/hip_runtime.h>
#include <hip/hip_bf16.h>

// B=2, S=2048, E=1024, H=16, HD=KD=VD=64. fp32 I/O, bf16 MFMA internals.
// R7: attn occupancy fix — 64-row q-tiles, grid 1024 (4 blocks/CU, 16 waves/CU).
// S^T formulation retained: P^T stays in registers as PV B-fragment.
#define SS 2048
#define EE 1024
#define SCALE 0.125f
#define LOG2E 1.44269504088896f

typedef __attribute__((ext_vector_type(8))) short short8;
typedef __attribute__((ext_vector_type(4))) float float4v;
typedef __attribute__((ext_vector_type(8))) unsigned short ushort8;
typedef __attribute__((ext_vector_type(4))) unsigned int uint4v;

__device__ __forceinline__ float bf2f(unsigned short u) {
  unsigned int v = ((unsigned int)u) << 16;
  return __uint_as_float(v);
}
__device__ __forceinline__ unsigned short f2bf(float f) {
  unsigned int u = __float_as_uint(f);
  unsigned int lsb = (u >> 16) & 1u;
  u += 0x7fffu + lsb;           // RNE
  return (unsigned short)(u >> 16);
}
__device__ __forceinline__ unsigned int pk2bf(float a, float b) {
  __hip_bfloat162 h = __float22bfloat162_rn(float2{a, b});
  return *reinterpret_cast<unsigned int*>(&h);
}

// ---------------------------------------------------------------------------
// Kernel 0: W3T[n'][d] bf16, n' = mtx*64+n, from Wq/Wk/Wv fp32 [d][n].
// ---------------------------------------------------------------------------
__global__ __launch_bounds__(256) void w3t_prep(
    const float* __restrict__ Wq, const float* __restrict__ Wk,
    const float* __restrict__ Wv, unsigned short* __restrict__ W3T)
{
  __shared__ unsigned short t[64 * 65];
  const float* W = (blockIdx.x == 0) ? Wq : (blockIdx.x == 1 ? Wk : Wv);
  int tid = threadIdx.x;
#pragma unroll
  for (int i = 0; i < 16; ++i) {
    int e = tid + i * 256; int d = e >> 6, n = e & 63;
    t[n * 65 + d] = f2bf(W[e]);
  }
  __syncthreads();
  unsigned short* dst = W3T + blockIdx.x * 4096;
#pragma unroll
  for (int i = 0; i < 16; ++i) {
    int e = tid + i * 256; int n = e >> 6, d = e & 63;
    dst[n * 64 + d] = t[n * 65 + d];
  }
}

// ---------------------------------------------------------------------------
// Kernel 1: QKV projection MFMA GEMM. Block = 128 s-rows of one bh (2 slabs
// of 64), W3T staged once per block. V written with the PV k-permutation:
// Vp[bh][s/32][d][pos], pos = ((s>>2)&3)*8 + ((s>>4)&1)*4 + (s&3).
// ---------------------------------------------------------------------------
__global__ __launch_bounds__(256) void qkv_kernel(
    const float* __restrict__ x, const unsigned short* __restrict__ W3T,
    const float* __restrict__ bq, const float* __restrict__ bk,
    const float* __restrict__ bv,
    unsigned short* __restrict__ Q, unsigned short* __restrict__ K,
    unsigned short* __restrict__ Vp)
{
  __shared__ __align__(16) unsigned short w3t[192 * 72];
  __shared__ __align__(16) unsigned short xt[64 * 72];
  __shared__ float sBias[192];
  int tid = threadIdx.x;
  int bh = blockIdx.x >> 4;
  int s0blk = (blockIdx.x & 15) * 128;
  int b = bh >> 4, h = bh & 15;
  int wv = tid >> 6, lane = tid & 63;
  int li = lane & 15, g = lane >> 4;

#pragma unroll
  for (int i = 0; i < 6; ++i) {
    int slot = tid + i * 256;
    int row = slot >> 3, c = slot & 7;
    *(short8*)(w3t + row * 72 + c * 8) = *(const short8*)(W3T + slot * 8);
  }
  if (tid < 192) sBias[tid] = (tid < 64) ? bq[tid] : (tid < 128 ? bk[tid - 64] : bv[tid - 128]);

  for (int half = 0; half < 2; ++half) {
    int s0 = s0blk + half * 64;
    if (half) __syncthreads();          // prior frag reads done before restage
    const float* xbase = x + ((size_t)(b * SS + s0)) * EE + h * 64;
#pragma unroll
    for (int it = 0; it < 4; ++it) {
      int flat = tid + it * 256;
      int row = flat >> 4, ch = flat & 15;
      float4 v = *(const float4*)(xbase + (size_t)row * EE + ch * 4);
      uint2 u; u.x = pk2bf(v.x, v.y); u.y = pk2bf(v.z, v.w);
      *(uint2*)(xt + row * 72 + ch * 4) = u;
    }
    __syncthreads();

    int mrow = wv * 16;
    short8 af[2];
#pragma unroll
    for (int ks = 0; ks < 2; ++ks)
      af[ks] = *(const short8*)(xt + (mrow + li) * 72 + ks * 32 + g * 8);

    float4v acc[12];
#pragma unroll
    for (int i = 0; i < 12; ++i) acc[i] = (float4v){0, 0, 0, 0};
#pragma unroll
    for (int ks = 0; ks < 2; ++ks)
#pragma unroll
      for (int nb = 0; nb < 12; ++nb) {
        short8 bfr = *(const short8*)(w3t + (nb * 16 + li) * 72 + ks * 32 + g * 8);
        acc[nb] = __builtin_amdgcn_mfma_f32_16x16x32_bf16(af[ks], bfr, acc[nb], 0, 0, 0);
      }

    int srow0 = s0 + mrow + g * 4;
#pragma unroll
    for (int nb = 0; nb < 12; ++nb) {
      float bias = sBias[nb * 16 + li];
      int mtx = nb >> 2, sub = nb & 3;
#pragma unroll
      for (int r = 0; r < 4; ++r) {
        unsigned short ob = f2bf(acc[nb][r] + bias);
        int s = srow0 + r;
        if (mtx == 0)      Q[((size_t)bh * SS + s) * 64 + sub * 16 + li] = ob;
        else if (mtx == 1) K[((size_t)bh * SS + s) * 64 + sub * 16 + li] = ob;
        else {
          int sl = s & 31;
          int pos = ((sl >> 2) & 3) * 8 + ((sl >> 4) & 1) * 4 + (sl & 3);
          Vp[(size_t)bh * 131072 + (size_t)(s >> 5) * 2048 + (sub * 16 + li) * 32 + pos] = ob;
        }
      }
    }
  }
}

// ---------------------------------------------------------------------------
// Kernel 2: pack mask in B-frag j-order, folding SCALE*log2(e).
// maskP[((qt*64+step)*64 + lane)*8 + j] =
//   bf16(c * mask[qt*16+li][step*32 + (j>>2)*16 + g*4 + (j&3)]),  lane=g*16+li.
// ---------------------------------------------------------------------------
__global__ __launch_bounds__(256) void mask_prep(
    const float* __restrict__ mask, unsigned short* __restrict__ maskP)
{
  int idx = blockIdx.x * 256 + threadIdx.x;
  int lane = idx & 63, step = (idx >> 6) & 63, qt = idx >> 12;
  int li = lane & 15, g = lane >> 4;
  const float c = SCALE * LOG2E;
  const float* mrow = mask + (size_t)(qt * 16 + li) * SS + step * 32 + g * 4;
  float4 a = *(const float4*)mrow;
  float4 bb = *(const float4*)(mrow + 16);
  uint4v o;
  o.x = pk2bf(a.x * c, a.y * c);
  o.y = pk2bf(a.z * c, a.w * c);
  o.z = pk2bf(bb.x * c, bb.y * c);
  o.w = pk2bf(bb.z * c, bb.w * c);
  *(uint4v*)(maskP + (size_t)idx * 8) = o;
}

// ---------------------------------------------------------------------------
// Kernel 3: flash attention, S^T formulation. Block = 64 q-rows of one bh
// (4 waves x 16 q). Grid 1024 = 4 blocks/CU. Double-buffered K/V LDS tiles,
// 1 barrier/step. QK: A=K rows, B=Q rows -> P^T in C/D (q=li, s=(g,r)) ->
// exp in-register -> PV: A=V^T (pos-permuted k), B=P^T. O^T -> O via LDS once.
// ---------------------------------------------------------------------------
__global__ __launch_bounds__(256) void attn_kernel(
    const unsigned short* __restrict__ Q, const unsigned short* __restrict__ K,
    const unsigned short* __restrict__ Vp, const unsigned short* __restrict__ maskP,
    unsigned short* __restrict__ AO)
{
  __shared__ __align__(16) unsigned short lds[2 * 2816 + 2 * 2560];
  unsigned short* ktb0 = lds;
  unsigned short* ktb1 = lds + 2816;
  unsigned short* vtb0 = lds + 5632;
  unsigned short* vtb1 = lds + 8192;

  int tid = threadIdx.x, wv = tid >> 6, lane = tid & 63;
  int li = lane & 15, g = lane >> 4;
  int bh = blockIdx.x >> 5;
  int q0 = (blockIdx.x & 31) * 64 + wv * 16;

  const unsigned short* Qb = Q + ((size_t)bh * SS + q0 + li) * 64;
  short8 qf0 = *(const short8*)(Qb + g * 8);
  short8 qf1 = *(const short8*)(Qb + 32 + g * 8);

  const unsigned short* Kg = K + (size_t)bh * SS * 64 + tid * 8;
  const unsigned short* Vg = Vp + (size_t)bh * 131072 + tid * 8;
  const unsigned short* Mg = maskP + (size_t)(q0 >> 4) * 32768 + lane * 8;
  int kldso = (tid >> 3) * 88 + (tid & 7) * 8;
  int vldso = (tid >> 2) * 40 + (tid & 3) * 8;

  float4v acc[4];
#pragma unroll
  for (int nb = 0; nb < 4; ++nb) acc[nb] = (float4v){0, 0, 0, 0};
  float2 den2 = {0.f, 0.f};

  short8 kreg = *(const short8*)Kg;
  short8 vreg = *(const short8*)Vg;
  uint4v mc = *(const uint4v*)Mg;
  *(short8*)(ktb0 + kldso) = kreg;
  *(short8*)(vtb0 + vldso) = vreg;
  __syncthreads();

  for (int step = 0; step < 64; ++step) {
    const unsigned short* kt = (step & 1) ? ktb1 : ktb0;
    const unsigned short* vt = (step & 1) ? vtb1 : vtb0;
    unsigned short* ktn = (step & 1) ? ktb0 : ktb1;
    unsigned short* vtn = (step & 1) ? vtb0 : vtb1;
    int ns = (step + 1) & 63;               // redundant tail prefetch
    kreg = *(const short8*)(Kg + (size_t)ns * 2048);
    vreg = *(const short8*)(Vg + (size_t)ns * 2048);
    uint4v mn = *(const uint4v*)(Mg + (size_t)ns * 512);

    short8 kf[2][2];
#pragma unroll
    for (int sb = 0; sb < 2; ++sb) {
      kf[sb][0] = *(const short8*)(kt + (sb * 16 + li) * 88 + g * 8);
      kf[sb][1] = *(const short8*)(kt + (sb * 16 + li) * 88 + 32 + g * 8);
    }

    uint4v pw;
#pragma unroll
    for (int sb = 0; sb < 2; ++sb) {
      float4v st = {0, 0, 0, 0};
      st = __builtin_amdgcn_mfma_f32_16x16x32_bf16(kf[sb][0], qf0, st, 0, 0, 0);
      st = __builtin_amdgcn_mfma_f32_16x16x32_bf16(kf[sb][1], qf1, st, 0, 0, 0);
#pragma unroll
      for (int hh = 0; hh < 2; ++hh) {
        unsigned int mm = mc[sb * 2 + hh];
        float mlo = __uint_as_float(mm << 16);
        float mhi = __uint_as_float(mm & 0xffff0000u);
        float p0 = __builtin_amdgcn_exp2f(st[2 * hh] * mlo);
        float p1 = __builtin_amdgcn_exp2f(st[2 * hh + 1] * mhi);
        den2.x += p0;
        den2.y += p1;
        pw[sb * 2 + hh] = pk2bf(p0, p1);
      }
    }
    short8 pf = *(short8*)&pw;
#pragma unroll
    for (int nb = 0; nb < 4; ++nb) {
      short8 vf = *(const short8*)(vt + (nb * 16 + li) * 40 + g * 8);
      acc[nb] = __builtin_amdgcn_mfma_f32_16x16x32_bf16(vf, pf, acc[nb], 0, 0, 0);
    }
    *(short8*)(ktn + kldso) = kreg;
    *(short8*)(vtn + vldso) = vreg;
    mc = mn;
    __syncthreads();
  }

  // den reduce over g-groups (q lives at li), then O^T -> O via one LDS pass
  float d = den2.x + den2.y;
  d += __shfl_xor(d, 16, 64);
  d += __shfl_xor(d, 32, 64);
  float rd = 1.0f / d;

  unsigned short* tr = lds + wv * 1152;   // 16 rows x 72 per wave (aliases kt/vt)
#pragma unroll
  for (int nb = 0; nb < 4; ++nb) {
    int base = li * 72 + nb * 16 + g * 4;
    *(unsigned int*)(tr + base)     = pk2bf(acc[nb][0] * rd, acc[nb][1] * rd);
    *(unsigned int*)(tr + base + 2) = pk2bf(acc[nb][2] * rd, acc[nb][3] * rd);
  }
  asm volatile("s_waitcnt lgkmcnt(0)" ::: "memory");

  int b = bh >> 4, h = bh & 15;
  int rrow = lane >> 3, part = lane & 7;
#pragma unroll
  for (int i = 0; i < 2; ++i) {
    int row = i * 8 + rrow;
    short8 ov = *(const short8*)(tr + row * 72 + part * 8);
    *(short8*)(AO + ((size_t)(b * SS + q0 + row)) * EE + h * 64 + part * 8) = ov;
  }
}

// ---------------------------------------------------------------------------
// Kernel 4: transpose Wo (fp32 [k][n]) -> WoT (bf16 [n][k]); runs after attn
// (aliases maskP region).
// ---------------------------------------------------------------------------
__global__ __launch_bounds__(256) void transpose_wo(
    const float* __restrict__ Wo, unsigned short* __restrict__ WoT)
{
  __shared__ unsigned short t[64 * 65];
  int tid = threadIdx.x;
  int k0 = (blockIdx.x >> 4) * 64;
  int n0 = (blockIdx.x & 15) * 64;
#pragma unroll
  for (int i = 0; i < 16; ++i) {
    int idx = tid + i * 256;
    int k = idx >> 6, n = idx & 63;
    t[n * 65 + k] = f2bf(Wo[(size_t)(k0 + k) * 1024 + n0 + n]);
  }
  __syncthreads();
#pragma unroll
  for (int i = 0; i < 16; ++i) {
    int idx = tid + i * 256;
    int n = idx >> 6, k = idx & 63;
    WoT[(size_t)(n0 + n) * 1024 + k0 + k] = t[n * 65 + k];
  }
}

// ---------------------------------------------------------------------------
// Kernel 5: out = AO(4096x1024 bf16) @ WoT^T + bo. 128m x 64n tile, BK=64,
// grid 512 (2 blocks/CU). Wave = 64m x 32n.
// ---------------------------------------------------------------------------
__global__ __launch_bounds__(256) void out_gemm(
    const unsigned short* __restrict__ AO, const unsigned short* __restrict__ WoT,
    const float* __restrict__ bo, float* __restrict__ out)
{
  __shared__ __align__(16) unsigned short at[128 * 72];
  __shared__ __align__(16) unsigned short bt[64 * 72];
  int tid = threadIdx.x, wv = tid >> 6, lane = tid & 63;
  int li = lane & 15, g = lane >> 4;
  int m0 = (blockIdx.x >> 4) * 128;
  int n0 = (blockIdx.x & 15) * 64;
  int wm = (wv & 1) * 64, wn = (wv >> 1) * 32;

  const unsigned short* Ag = AO + (size_t)m0 * 1024;
  const unsigned short* Bg = WoT + (size_t)n0 * 1024;
  int srow = tid >> 3, scol = (tid & 7) * 8;

  short8 apre[4], bpre[2];
  auto ldst = [&](int k0) {
#pragma unroll
    for (int i = 0; i < 4; ++i)
      apre[i] = *(const short8*)(Ag + (size_t)(srow + i * 32) * 1024 + k0 + scol);
#pragma unroll
    for (int i = 0; i < 2; ++i)
      bpre[i] = *(const short8*)(Bg + (size_t)(srow + i * 32) * 1024 + k0 + scol);
  };

  float4v acc[4][2];
#pragma unroll
  for (int mt = 0; mt < 4; ++mt)
#pragma unroll
    for (int nt = 0; nt < 2; ++nt) acc[mt][nt] = (float4v){0, 0, 0, 0};

  ldst(0);
  for (int k0 = 0; k0 < 1024; k0 += 64) {
    __syncthreads();
#pragma unroll
    for (int i = 0; i < 4; ++i)
      *(short8*)(at + (srow + i * 32) * 72 + scol) = apre[i];
#pragma unroll
    for (int i = 0; i < 2; ++i)
      *(short8*)(bt + (srow + i * 32) * 72 + scol) = bpre[i];
    int nk = (k0 + 64 < 1024) ? k0 + 64 : 0;
    ldst(nk);
    __syncthreads();
#pragma unroll
    for (int ks = 0; ks < 2; ++ks) {
      short8 afr[4], bfr[2];
#pragma unroll
      for (int mt = 0; mt < 4; ++mt)
        afr[mt] = *(const short8*)(at + (wm + mt * 16 + li) * 72 + ks * 32 + g * 8);
#pragma unroll
      for (int nt = 0; nt < 2; ++nt)
        bfr[nt] = *(const short8*)(bt + (wn + nt * 16 + li) * 72 + ks * 32 + g * 8);
#pragma unroll
      for (int mt = 0; mt < 4; ++mt)
#pragma unroll
        for (int nt = 0; nt < 2; ++nt)
          acc[mt][nt] = __builtin_amdgcn_mfma_f32_16x16x32_bf16(afr[mt], bfr[nt], acc[mt][nt], 0, 0, 0);
    }
  }
#pragma unroll
  for (int nt = 0; nt < 2; ++nt) {
    float bof = bo[n0 + wn + nt * 16 + li];
#pragma unroll
    for (int mt = 0; mt < 4; ++mt)
#pragma unroll
      for (int r = 0; r < 4; ++r)
        out[(size_t)(m0 + wm + mt * 16 + g * 4 + r) * 1024 + n0 + wn + nt * 16 + li] =
            acc[mt][nt][r] + bof;
  }
}

// ---------------------------------------------------------------------------
extern "C" void kernel_launch(void* const* d_in, const int* in_sizes, int n_in,
                              void* d_out, int out_size, void* d_ws, size_t ws_size,
                              hipStream_t stream) {
  const float* x    = (const float*)d_in[0];
  const float* mask = (const float*)d_in[1];
  const float* Wq   = (const float*)d_in[2];
  const float* bq   = (const float*)d_in[3];
  const float* Wk   = (const float*)d_in[4];
  const float* bk   = (const float*)d_in[5];
  const float* Wv   = (const float*)d_in[6];
  const float* bv   = (const float*)d_in[7];
  const float* Wo   = (const float*)d_in[8];
  const float* bo   = (const float*)d_in[9];
  float* out = (float*)d_out;

  unsigned short* ws = (unsigned short*)d_ws;
  unsigned short* Q     = ws;
  unsigned short* K     = ws + 4194304;
  unsigned short* Vp    = ws + 8388608;
  unsigned short* AO    = ws + 12582912;
  unsigned short* maskP = ws + 16777216;
  unsigned short* W3T = AO;      // dead until attn writes AO
  unsigned short* WoT = maskP;   // dead after attn reads maskP

  w3t_prep<<<3, 256, 0, stream>>>(Wq, Wk, Wv, W3T);
  qkv_kernel<<<512, 256, 0, stream>>>(x, W3T, bq, bk, bv, Q, K, Vp);
  mask_prep<<<2048, 256, 0, stream>>>(mask, maskP);
  attn_kernel<<<1024, 256, 0, stream>>>(Q, K, Vp, maskP, AO);
  transpose_wo<<<256, 256, 0, stream>>>(Wo, WoT);
  out_gemm<<<512, 256, 0, stream>>>(AO, WoT, bo, out);
}

// Round 8
// 189.873 us; speedup vs baseline: 1.0146x; 1.0146x over previous
//
#include <hip/hip_runtime.h>
#include <hip/hip_bf16.h>

// B=2, S=2048, E=1024, H=16, HD=KD=VD=64. fp32 I/O, bf16 MFMA internals.
// R8: fragment-order global packing for K and V -> all attn LDS ops are
// contiguous b128 (zero bank conflicts); den computed via ones-row MFMA.
#define SS 2048
#define EE 1024
#define SCALE 0.125f
#define LOG2E 1.44269504088896f

typedef __attribute__((ext_vector_type(8))) short short8;
typedef __attribute__((ext_vector_type(4))) float float4v;
typedef __attribute__((ext_vector_type(4))) unsigned int uint4v;

__device__ __forceinline__ unsigned short f2bf(float f) {
  unsigned int u = __float_as_uint(f);
  unsigned int lsb = (u >> 16) & 1u;
  u += 0x7fffu + lsb;           // RNE
  return (unsigned short)(u >> 16);
}
__device__ __forceinline__ unsigned int pk2bf(float a, float b) {
  __hip_bfloat162 h = __float22bfloat162_rn(float2{a, b});
  return *reinterpret_cast<unsigned int*>(&h);
}

// ---------------------------------------------------------------------------
// Kernel 1: prep = mask pack (blocks 0..2047) + W3T transpose (blocks 2048-50).
// maskP[((qt*64+step)*64+lane)*8 + j] = bf16(c * mask[qt*16+li][step*32 +
//   (j>>2)*16 + g*4 + (j&3)]), lane = g*16+li  (B-frag j-order, folds SCALE*log2e)
// ---------------------------------------------------------------------------
__global__ __launch_bounds__(256) void prep_kernel(
    const float* __restrict__ mask,
    const float* __restrict__ Wq, const float* __restrict__ Wk,
    const float* __restrict__ Wv,
    unsigned short* __restrict__ maskP, unsigned short* __restrict__ W3T)
{
  __shared__ unsigned short t[64 * 65];
  int blk = blockIdx.x;
  int tid = threadIdx.x;
  if (blk < 2048) {
    int idx = blk * 256 + tid;
    int lane = idx & 63, step = (idx >> 6) & 63, qt = idx >> 12;
    int li = lane & 15, g = lane >> 4;
    const float c = SCALE * LOG2E;
    const float* mrow = mask + (size_t)(qt * 16 + li) * SS + step * 32 + g * 4;
    float4 a = *(const float4*)mrow;
    float4 bb = *(const float4*)(mrow + 16);
    uint4v o;
    o.x = pk2bf(a.x * c, a.y * c);
    o.y = pk2bf(a.z * c, a.w * c);
    o.z = pk2bf(bb.x * c, bb.y * c);
    o.w = pk2bf(bb.z * c, bb.w * c);
    *(uint4v*)(maskP + (size_t)idx * 8) = o;
    return;
  }
  int m = blk - 2048;
  const float* W = (m == 0) ? Wq : (m == 1 ? Wk : Wv);
#pragma unroll
  for (int i = 0; i < 16; ++i) {
    int e = tid + i * 256; int d = e >> 6, n = e & 63;
    t[n * 65 + d] = f2bf(W[e]);
  }
  __syncthreads();
  unsigned short* dst = W3T + m * 4096;
#pragma unroll
  for (int i = 0; i < 16; ++i) {
    int e = tid + i * 256; int n = e >> 6, d = e & 63;
    dst[n * 64 + d] = t[n * 65 + d];
  }
}

// ---------------------------------------------------------------------------
// Kernel 2: QKV projection MFMA GEMM. Block = 128 s-rows of one bh.
// Q row-major. K and V written in ATTN FRAGMENT ORDER:
//  Kp[bh][step][frag=sb*2+part][lane=g*16+(s&15)][j] = K[s][part*32+g*8+j]
//  Vf[bh][step][nb][lane=(pos>>3)*16+(d&15)][pos&7]  = V[s][d], pos = perm(s&31)
// ---------------------------------------------------------------------------
__global__ __launch_bounds__(256) void qkv_kernel(
    const float* __restrict__ x, const unsigned short* __restrict__ W3T,
    const float* __restrict__ bq, const float* __restrict__ bk,
    const float* __restrict__ bv,
    unsigned short* __restrict__ Q, unsigned short* __restrict__ Kp,
    unsigned short* __restrict__ Vf)
{
  __shared__ __align__(16) unsigned short w3t[192 * 72];
  __shared__ __align__(16) unsigned short xt[64 * 72];
  __shared__ float sBias[192];
  int tid = threadIdx.x;
  int bh = blockIdx.x >> 4;
  int s0blk = (blockIdx.x & 15) * 128;
  int b = bh >> 4, h = bh & 15;
  int wv = tid >> 6, lane = tid & 63;
  int li = lane & 15, g = lane >> 4;

#pragma unroll
  for (int i = 0; i < 6; ++i) {
    int slot = tid + i * 256;
    int row = slot >> 3, c = slot & 7;
    *(short8*)(w3t + row * 72 + c * 8) = *(const short8*)(W3T + slot * 8);
  }
  if (tid < 192) sBias[tid] = (tid < 64) ? bq[tid] : (tid < 128 ? bk[tid - 64] : bv[tid - 128]);

  for (int half = 0; half < 2; ++half) {
    int s0 = s0blk + half * 64;
    if (half) __syncthreads();
    const float* xbase = x + ((size_t)(b * SS + s0)) * EE + h * 64;
#pragma unroll
    for (int it = 0; it < 4; ++it) {
      int flat = tid + it * 256;
      int row = flat >> 4, ch = flat & 15;
      float4 v = *(const float4*)(xbase + (size_t)row * EE + ch * 4);
      uint2 u; u.x = pk2bf(v.x, v.y); u.y = pk2bf(v.z, v.w);
      *(uint2*)(xt + row * 72 + ch * 4) = u;
    }
    __syncthreads();

    int mrow = wv * 16;
    short8 af[2];
#pragma unroll
    for (int ks = 0; ks < 2; ++ks)
      af[ks] = *(const short8*)(xt + (mrow + li) * 72 + ks * 32 + g * 8);

    float4v acc[12];
#pragma unroll
    for (int i = 0; i < 12; ++i) acc[i] = (float4v){0, 0, 0, 0};
#pragma unroll
    for (int ks = 0; ks < 2; ++ks)
#pragma unroll
      for (int nb = 0; nb < 12; ++nb) {
        short8 bfr = *(const short8*)(w3t + (nb * 16 + li) * 72 + ks * 32 + g * 8);
        acc[nb] = __builtin_amdgcn_mfma_f32_16x16x32_bf16(af[ks], bfr, acc[nb], 0, 0, 0);
      }

    int srow0 = s0 + mrow + g * 4;
#pragma unroll
    for (int nb = 0; nb < 12; ++nb) {
      float bias = sBias[nb * 16 + li];
      int mtx = nb >> 2, sub = nb & 3;
#pragma unroll
      for (int r = 0; r < 4; ++r) {
        unsigned short ob = f2bf(acc[nb][r] + bias);
        int s = srow0 + r;
        int step = s >> 5;
        if (mtx == 0) {
          Q[((size_t)bh * SS + s) * 64 + sub * 16 + li] = ob;
        } else if (mtx == 1) {
          int sb = (s >> 4) & 1, lik = s & 15;
          int part = sub >> 1;
          int gk = ((sub & 1) << 1) | (li >> 3);
          Kp[(size_t)bh * 131072 + step * 2048 + (sb * 2 + part) * 512 +
             (gk * 16 + lik) * 8 + (li & 7)] = ob;
        } else {
          int sl = s & 31;
          int pos = ((sl >> 2) & 3) * 8 + ((sl >> 4) & 1) * 4 + (sl & 3);
          Vf[(size_t)bh * 131072 + step * 2048 + sub * 512 +
             ((pos >> 3) * 16 + li) * 8 + (pos & 7)] = ob;
        }
      }
    }
  }
}

// ---------------------------------------------------------------------------
// Kernel 3: flash attention. Block = 64 q-rows of one bh (4 waves x 16 q),
// grid 1024. Fragment-order LDS tiles: staging = 1 contiguous b128/thread,
// fragment reads = contiguous b128 (zero bank conflicts). den via ones-row
// MFMA. S^T formulation; O^T -> O via one LDS pass at end.
// ---------------------------------------------------------------------------
__global__ __launch_bounds__(256) void attn_kernel(
    const unsigned short* __restrict__ Q, const unsigned short* __restrict__ Kp,
    const unsigned short* __restrict__ Vf, const unsigned short* __restrict__ maskP,
    unsigned short* __restrict__ AO)
{
  __shared__ __align__(16) unsigned short lds[8192];  // kt0 vt0 kt1 vt1 (2048 each)
  int tid = threadIdx.x, wv = tid >> 6, lane = tid & 63;
  int li = lane & 15, g = lane >> 4;
  int bh = blockIdx.x >> 5;
  int q0 = (blockIdx.x & 31) * 64 + wv * 16;

  const unsigned short* Qb = Q + ((size_t)bh * SS + q0 + li) * 64;
  short8 qf0 = *(const short8*)(Qb + g * 8);
  short8 qf1 = *(const short8*)(Qb + 32 + g * 8);

  const unsigned short* Kg = Kp + (size_t)bh * 131072 + tid * 8;
  const unsigned short* Vg = Vf + (size_t)bh * 131072 + tid * 8;
  const unsigned short* Mg = maskP + (size_t)(q0 >> 4) * 32768 + lane * 8;

  // ones-row V tile for denominator: A[m=li][k] = (li==0) ? 1.0bf : 0
  unsigned short ov = (li == 0) ? (unsigned short)0x3F80 : (unsigned short)0;
  short8 vones = {(short)ov, (short)ov, (short)ov, (short)ov,
                  (short)ov, (short)ov, (short)ov, (short)ov};

  float4v acc[4];
#pragma unroll
  for (int nb = 0; nb < 4; ++nb) acc[nb] = (float4v){0, 0, 0, 0};
  float4v accd = {0, 0, 0, 0};

  short8 kreg = *(const short8*)Kg;
  short8 vreg = *(const short8*)Vg;
  uint4v mc = *(const uint4v*)Mg;
  *(short8*)(lds + tid * 8) = kreg;          // kt0
  *(short8*)(lds + 2048 + tid * 8) = vreg;   // vt0
  __syncthreads();

  for (int step = 0; step < 64; ++step) {
    const unsigned short* ktc = lds + ((step & 1) ? 4096 : 0);
    const unsigned short* vtc = ktc + 2048;
    unsigned short* ktn = lds + ((step & 1) ? 0 : 4096);
    unsigned short* vtn = ktn + 2048;
    int ns = (step + 1) & 63;                // redundant tail prefetch
    kreg = *(const short8*)(Kg + (size_t)ns * 2048);
    vreg = *(const short8*)(Vg + (size_t)ns * 2048);
    uint4v mn = *(const uint4v*)(Mg + (size_t)ns * 512);

    short8 kf00 = *(const short8*)(ktc + lane * 8);
    short8 kf01 = *(const short8*)(ktc + 512 + lane * 8);
    short8 kf10 = *(const short8*)(ktc + 1024 + lane * 8);
    short8 kf11 = *(const short8*)(ktc + 1536 + lane * 8);

    uint4v pw;
    {
      float4v st = {0, 0, 0, 0};
      st = __builtin_amdgcn_mfma_f32_16x16x32_bf16(kf00, qf0, st, 0, 0, 0);
      st = __builtin_amdgcn_mfma_f32_16x16x32_bf16(kf01, qf1, st, 0, 0, 0);
#pragma unroll
      for (int hh = 0; hh < 2; ++hh) {
        unsigned int mm = mc[hh];
        float p0 = __builtin_amdgcn_exp2f(st[2 * hh] * __uint_as_float(mm << 16));
        float p1 = __builtin_amdgcn_exp2f(st[2 * hh + 1] * __uint_as_float(mm & 0xffff0000u));
        pw[hh] = pk2bf(p0, p1);
      }
    }
    {
      float4v st = {0, 0, 0, 0};
      st = __builtin_amdgcn_mfma_f32_16x16x32_bf16(kf10, qf0, st, 0, 0, 0);
      st = __builtin_amdgcn_mfma_f32_16x16x32_bf16(kf11, qf1, st, 0, 0, 0);
#pragma unroll
      for (int hh = 0; hh < 2; ++hh) {
        unsigned int mm = mc[2 + hh];
        float p0 = __builtin_amdgcn_exp2f(st[2 * hh] * __uint_as_float(mm << 16));
        float p1 = __builtin_amdgcn_exp2f(st[2 * hh + 1] * __uint_as_float(mm & 0xffff0000u));
        pw[2 + hh] = pk2bf(p0, p1);
      }
    }
    short8 pf = *(short8*)&pw;
#pragma unroll
    for (int nb = 0; nb < 4; ++nb) {
      short8 vfr = *(const short8*)(vtc + nb * 512 + lane * 8);
      acc[nb] = __builtin_amdgcn_mfma_f32_16x16x32_bf16(vfr, pf, acc[nb], 0, 0, 0);
    }
    accd = __builtin_amdgcn_mfma_f32_16x16x32_bf16(vones, pf, accd, 0, 0, 0);

    *(short8*)(ktn + tid * 8) = kreg;
    *(short8*)(vtn + tid * 8) = vreg;
    mc = mn;
    __syncthreads();
  }

  // den[q=li] lives in lane li (row 0 of accd). Broadcast & invert.
  float den = __shfl(accd[0], li, 64);
  float rd = 1.0f / den;

  // O^T -> O via per-wave LDS region (reuses tile memory; all waves past barrier)
  unsigned short* tr = lds + wv * 1152;   // 16 rows x 72
#pragma unroll
  for (int nb = 0; nb < 4; ++nb) {
    int base = li * 72 + nb * 16 + g * 4;
    *(unsigned int*)(tr + base)     = pk2bf(acc[nb][0] * rd, acc[nb][1] * rd);
    *(unsigned int*)(tr + base + 2) = pk2bf(acc[nb][2] * rd, acc[nb][3] * rd);
  }
  asm volatile("s_waitcnt lgkmcnt(0)" ::: "memory");

  int b = bh >> 4, h = bh & 15;
  int rrow = lane >> 3, part = lane & 7;
#pragma unroll
  for (int i = 0; i < 2; ++i) {
    int row = i * 8 + rrow;
    short8 o = *(const short8*)(tr + row * 72 + part * 8);
    *(short8*)(AO + ((size_t)(b * SS + q0 + row)) * EE + h * 64 + part * 8) = o;
  }
}

// ---------------------------------------------------------------------------
// Kernel 4: transpose Wo (fp32 [k][n]) -> WoT (bf16 [n][k]); after attn,
// aliases maskP region.
// ---------------------------------------------------------------------------
__global__ __launch_bounds__(256) void transpose_wo(
    const float* __restrict__ Wo, unsigned short* __restrict__ WoT)
{
  __shared__ unsigned short t[64 * 65];
  int tid = threadIdx.x;
  int k0 = (blockIdx.x >> 4) * 64;
  int n0 = (blockIdx.x & 15) * 64;
#pragma unroll
  for (int i = 0; i < 16; ++i) {
    int idx = tid + i * 256;
    int k = idx >> 6, n = idx & 63;
    t[n * 65 + k] = f2bf(Wo[(size_t)(k0 + k) * 1024 + n0 + n]);
  }
  __syncthreads();
#pragma unroll
  for (int i = 0; i < 16; ++i) {
    int idx = tid + i * 256;
    int n = idx >> 6, k = idx & 63;
    WoT[(size_t)(n0 + n) * 1024 + k0 + k] = t[n * 65 + k];
  }
}

// ---------------------------------------------------------------------------
// Kernel 5: out = AO(4096x1024 bf16) @ WoT^T + bo. 128m x 64n tile, BK=64,
// grid 512 (2 blocks/CU). Wave = 64m x 32n.
// ---------------------------------------------------------------------------
__global__ __launch_bounds__(256) void out_gemm(
    const unsigned short* __restrict__ AO, const unsigned short* __restrict__ WoT,
    const float* __restrict__ bo, float* __restrict__ out)
{
  __shared__ __align__(16) unsigned short at[128 * 72];
  __shared__ __align__(16) unsigned short bt[64 * 72];
  int tid = threadIdx.x, wv = tid >> 6, lane = tid & 63;
  int li = lane & 15, g = lane >> 4;
  int m0 = (blockIdx.x >> 4) * 128;
  int n0 = (blockIdx.x & 15) * 64;
  int wm = (wv & 1) * 64, wn = (wv >> 1) * 32;

  const unsigned short* Ag = AO + (size_t)m0 * 1024;
  const unsigned short* Bg = WoT + (size_t)n0 * 1024;
  int srow = tid >> 3, scol = (tid & 7) * 8;

  short8 apre[4], bpre[2];
  auto ldst = [&](int k0) {
#pragma unroll
    for (int i = 0; i < 4; ++i)
      apre[i] = *(const short8*)(Ag + (size_t)(srow + i * 32) * 1024 + k0 + scol);
#pragma unroll
    for (int i = 0; i < 2; ++i)
      bpre[i] = *(const short8*)(Bg + (size_t)(srow + i * 32) * 1024 + k0 + scol);
  };

  float4v acc[4][2];
#pragma unroll
  for (int mt = 0; mt < 4; ++mt)
#pragma unroll
    for (int nt = 0; nt < 2; ++nt) acc[mt][nt] = (float4v){0, 0, 0, 0};

  ldst(0);
  for (int k0 = 0; k0 < 1024; k0 += 64) {
    __syncthreads();
#pragma unroll
    for (int i = 0; i < 4; ++i)
      *(short8*)(at + (srow + i * 32) * 72 + scol) = apre[i];
#pragma unroll
    for (int i = 0; i < 2; ++i)
      *(short8*)(bt + (srow + i * 32) * 72 + scol) = bpre[i];
    int nk = (k0 + 64 < 1024) ? k0 + 64 : 0;
    ldst(nk);
    __syncthreads();
#pragma unroll
    for (int ks = 0; ks < 2; ++ks) {
      short8 afr[4], bfr[2];
#pragma unroll
      for (int mt = 0; mt < 4; ++mt)
        afr[mt] = *(const short8*)(at + (wm + mt * 16 + li) * 72 + ks * 32 + g * 8);
#pragma unroll
      for (int nt = 0; nt < 2; ++nt)
        bfr[nt] = *(const short8*)(bt + (wn + nt * 16 + li) * 72 + ks * 32 + g * 8);
#pragma unroll
      for (int mt = 0; mt < 4; ++mt)
#pragma unroll
        for (int nt = 0; nt < 2; ++nt)
          acc[mt][nt] = __builtin_amdgcn_mfma_f32_16x16x32_bf16(afr[mt], bfr[nt], acc[mt][nt], 0, 0, 0);
    }
  }
#pragma unroll
  for (int nt = 0; nt < 2; ++nt) {
    float bof = bo[n0 + wn + nt * 16 + li];
#pragma unroll
    for (int mt = 0; mt < 4; ++mt)
#pragma unroll
      for (int r = 0; r < 4; ++r)
        out[(size_t)(m0 + wm + mt * 16 + g * 4 + r) * 1024 + n0 + wn + nt * 16 + li] =
            acc[mt][nt][r] + bof;
  }
}

// ---------------------------------------------------------------------------
extern "C" void kernel_launch(void* const* d_in, const int* in_sizes, int n_in,
                              void* d_out, int out_size, void* d_ws, size_t ws_size,
                              hipStream_t stream) {
  const float* x    = (const float*)d_in[0];
  const float* mask = (const float*)d_in[1];
  const float* Wq   = (const float*)d_in[2];
  const float* bq   = (const float*)d_in[3];
  const float* Wk   = (const float*)d_in[4];
  const float* bk   = (const float*)d_in[5];
  const float* Wv   = (const float*)d_in[6];
  const float* bv   = (const float*)d_in[7];
  const float* Wo   = (const float*)d_in[8];
  const float* bo   = (const float*)d_in[9];
  float* out = (float*)d_out;

  unsigned short* ws = (unsigned short*)d_ws;
  unsigned short* Q     = ws;
  unsigned short* Kp    = ws + 4194304;
  unsigned short* Vf    = ws + 8388608;
  unsigned short* AO    = ws + 12582912;
  unsigned short* maskP = ws + 16777216;
  unsigned short* W3T = AO;      // dead until attn writes AO
  unsigned short* WoT = maskP;   // dead after attn reads maskP

  prep_kernel<<<2051, 256, 0, stream>>>(mask, Wq, Wk, Wv, maskP, W3T);
  qkv_kernel<<<512, 256, 0, stream>>>(x, W3T, bq, bk, bv, Q, Kp, Vf);
  attn_kernel<<<1024, 256, 0, stream>>>(Q, Kp, Vf, maskP, AO);
  transpose_wo<<<256, 256, 0, stream>>>(Wo, WoT);
  out_gemm<<<512, 256, 0, stream>>>(AO, WoT, bo, out);
}

// Round 9
// 186.825 us; speedup vs baseline: 1.0312x; 1.0163x over previous
//
#include <hip/hip_runtime.h>
#include <hip/hip_bf16.h>

// B=2, S=2048, E=1024, H=16, HD=KD=VD=64. fp32 I/O, bf16 MFMA internals.
// R9: attn = barrier-free, LDS-free K-loop (direct global fragment loads,
// 32q/wave); qkv = LDS-coalesced output staging; Wo transpose folded into
// out_gemm (4 launches).
#define SS 2048
#define EE 1024
#define SCALE 0.125f
#define LOG2E 1.44269504088896f

typedef __attribute__((ext_vector_type(8))) short short8;
typedef __attribute__((ext_vector_type(4))) float float4v;
typedef __attribute__((ext_vector_type(4))) unsigned int uint4v;

__device__ __forceinline__ unsigned short f2bf(float f) {
  unsigned int u = __float_as_uint(f);
  unsigned int lsb = (u >> 16) & 1u;
  u += 0x7fffu + lsb;           // RNE
  return (unsigned short)(u >> 16);
}
__device__ __forceinline__ unsigned int pk2bf(float a, float b) {
  __hip_bfloat162 h = __float22bfloat162_rn(float2{a, b});
  return *reinterpret_cast<unsigned int*>(&h);
}

// ---------------------------------------------------------------------------
// Kernel 1: prep = mask pack (blocks 0..2047) + W3T transpose (2048..2050).
// maskP[((qt*64+step)*64+lane)*8 + j] = bf16(c * mask[qt*16+li][step*32 +
//   (j>>2)*16 + g*4 + (j&3)]), lane = g*16+li (B-frag j-order, folds SCALE*log2e)
// ---------------------------------------------------------------------------
__global__ __launch_bounds__(256) void prep_kernel(
    const float* __restrict__ mask,
    const float* __restrict__ Wq, const float* __restrict__ Wk,
    const float* __restrict__ Wv,
    unsigned short* __restrict__ maskP, unsigned short* __restrict__ W3T)
{
  __shared__ unsigned short t[64 * 65];
  int blk = blockIdx.x;
  int tid = threadIdx.x;
  if (blk < 2048) {
    int idx = blk * 256 + tid;
    int lane = idx & 63, step = (idx >> 6) & 63, qt = idx >> 12;
    int li = lane & 15, g = lane >> 4;
    const float c = SCALE * LOG2E;
    const float* mrow = mask + (size_t)(qt * 16 + li) * SS + step * 32 + g * 4;
    float4 a = *(const float4*)mrow;
    float4 bb = *(const float4*)(mrow + 16);
    uint4v o;
    o.x = pk2bf(a.x * c, a.y * c);
    o.y = pk2bf(a.z * c, a.w * c);
    o.z = pk2bf(bb.x * c, bb.y * c);
    o.w = pk2bf(bb.z * c, bb.w * c);
    *(uint4v*)(maskP + (size_t)idx * 8) = o;
    return;
  }
  int m = blk - 2048;
  const float* W = (m == 0) ? Wq : (m == 1 ? Wk : Wv);
#pragma unroll
  for (int i = 0; i < 16; ++i) {
    int e = tid + i * 256; int d = e >> 6, n = e & 63;
    t[n * 65 + d] = f2bf(W[e]);
  }
  __syncthreads();
  unsigned short* dst = W3T + m * 4096;
#pragma unroll
  for (int i = 0; i < 16; ++i) {
    int e = tid + i * 256; int n = e >> 6, d = e & 63;
    dst[n * 64 + d] = t[n * 65 + d];
  }
}

// ---------------------------------------------------------------------------
// Kernel 2: QKV projection MFMA GEMM. Block = 128 s-rows of one bh, 2 halves.
// Outputs routed through an LDS reorder buffer -> 6 coalesced b128 global
// stores per thread per half (Q row-major; Kp/Vf in attn fragment order).
//  Kp[bh][step][frag=sb*2+part][lane=g*16+(s&15)][j] = K[s][part*32+g*8+j]
//  Vf[bh][step][nb][lane=(pos>>3)*16+(d&15)][pos&7]  = V[s][d], pos=perm(s&31)
// ---------------------------------------------------------------------------
__global__ __launch_bounds__(256) void qkv_kernel(
    const float* __restrict__ x, const unsigned short* __restrict__ W3T,
    const float* __restrict__ bq, const float* __restrict__ bk,
    const float* __restrict__ bv,
    unsigned short* __restrict__ Q, unsigned short* __restrict__ Kp,
    unsigned short* __restrict__ Vf)
{
  __shared__ __align__(16) unsigned short w3t[192 * 72];
  __shared__ __align__(16) unsigned short xt[64 * 72];
  __shared__ __align__(16) unsigned short ob[12288];   // Q | Kp | Vf half-tile
  __shared__ float sBias[192];
  int tid = threadIdx.x;
  int bh = blockIdx.x >> 4;
  int s0blk = (blockIdx.x & 15) * 128;
  int b = bh >> 4, h = bh & 15;
  int wv = tid >> 6, lane = tid & 63;
  int li = lane & 15, g = lane >> 4;

#pragma unroll
  for (int i = 0; i < 6; ++i) {
    int slot = tid + i * 256;
    int row = slot >> 3, c = slot & 7;
    *(short8*)(w3t + row * 72 + c * 8) = *(const short8*)(W3T + slot * 8);
  }
  if (tid < 192) sBias[tid] = (tid < 64) ? bq[tid] : (tid < 128 ? bk[tid - 64] : bv[tid - 128]);

  for (int half = 0; half < 2; ++half) {
    int s0 = s0blk + half * 64;
    if (half) __syncthreads();        // prior half's ob/xt reads done
    const float* xbase = x + ((size_t)(b * SS + s0)) * EE + h * 64;
#pragma unroll
    for (int it = 0; it < 4; ++it) {
      int flat = tid + it * 256;
      int row = flat >> 4, ch = flat & 15;
      float4 v = *(const float4*)(xbase + (size_t)row * EE + ch * 4);
      uint2 u; u.x = pk2bf(v.x, v.y); u.y = pk2bf(v.z, v.w);
      *(uint2*)(xt + row * 72 + ch * 4) = u;
    }
    __syncthreads();

    int mrow = wv * 16;
    short8 af[2];
#pragma unroll
    for (int ks = 0; ks < 2; ++ks)
      af[ks] = *(const short8*)(xt + (mrow + li) * 72 + ks * 32 + g * 8);

    float4v acc[12];
#pragma unroll
    for (int i = 0; i < 12; ++i) acc[i] = (float4v){0, 0, 0, 0};
#pragma unroll
    for (int ks = 0; ks < 2; ++ks)
#pragma unroll
      for (int nb = 0; nb < 12; ++nb) {
        short8 bfr = *(const short8*)(w3t + (nb * 16 + li) * 72 + ks * 32 + g * 8);
        acc[nb] = __builtin_amdgcn_mfma_f32_16x16x32_bf16(af[ks], bfr, acc[nb], 0, 0, 0);
      }

    // scatter into LDS reorder buffer
#pragma unroll
    for (int nb = 0; nb < 12; ++nb) {
      float bias = sBias[nb * 16 + li];
      int mtx = nb >> 2, sub = nb & 3;
#pragma unroll
      for (int r = 0; r < 4; ++r) {
        unsigned short v = f2bf(acc[nb][r] + bias);
        int sl = mrow + g * 4 + r;         // 0..63 local row
        int stp = sl >> 5, s5 = sl & 31;
        if (mtx == 0) {
          ob[sl * 64 + sub * 16 + li] = v;
        } else if (mtx == 1) {
          int sb = s5 >> 4, lik = s5 & 15;
          int part = sub >> 1;
          int gk = ((sub & 1) << 1) | (li >> 3);
          ob[4096 + stp * 2048 + (sb * 2 + part) * 512 + (gk * 16 + lik) * 8 + (li & 7)] = v;
        } else {
          int pos = ((s5 >> 2) & 3) * 8 + ((s5 >> 4) & 1) * 4 + (s5 & 3);
          ob[8192 + stp * 2048 + sub * 512 + ((pos >> 3) * 16 + li) * 8 + (pos & 7)] = v;
        }
      }
    }
    __syncthreads();

    // coalesced b128 stores: 1536 slots of 8 elems
    unsigned short* Qg = Q + ((size_t)bh * SS + s0) * 64;
    unsigned short* Kg = Kp + (size_t)bh * 131072 + (s0 >> 5) * 2048;
    unsigned short* Vg = Vf + (size_t)bh * 131072 + (s0 >> 5) * 2048;
#pragma unroll
    for (int i = 0; i < 6; ++i) {
      int slot = tid + i * 256;          // 0..1535
      int rgn = slot >> 9, off = (slot & 511) * 8;
      short8 v = *(const short8*)(ob + rgn * 4096 + off);
      unsigned short* dst = (rgn == 0) ? (Qg + off) : (rgn == 1 ? (Kg + off) : (Vg + off));
      *(short8*)dst = v;
    }
  }
}

// ---------------------------------------------------------------------------
// Kernel 3: flash attention, barrier-free & LDS-free K-loop. Wave = 32 q-rows
// of one bh; block = 4 independent waves; grid 512. All K/V/mask fragments
// loaded directly global->registers (contiguous 1KB per wave-instruction).
// S^T formulation; den via ones-row MFMA; epilogue O^T->O via wave-private LDS.
// ---------------------------------------------------------------------------
__global__ __launch_bounds__(256) void attn_kernel(
    const unsigned short* __restrict__ Q, const unsigned short* __restrict__ Kp,
    const unsigned short* __restrict__ Vf, const unsigned short* __restrict__ maskP,
    unsigned short* __restrict__ AO)
{
  __shared__ __align__(16) unsigned short tr_all[4 * 32 * 72];  // epilogue only
  int tid = threadIdx.x, wv = tid >> 6, lane = tid & 63;
  int li = lane & 15, g = lane >> 4;
  int wave_id = blockIdx.x * 4 + wv;        // 0..2047
  int bh = wave_id >> 6;
  int q0 = (wave_id & 63) * 32;

  short8 qf[2][2];
#pragma unroll
  for (int t = 0; t < 2; ++t) {
    const unsigned short* Qb = Q + ((size_t)bh * SS + q0 + t * 16 + li) * 64;
    qf[t][0] = *(const short8*)(Qb + g * 8);
    qf[t][1] = *(const short8*)(Qb + 32 + g * 8);
  }

  const unsigned short* Kg = Kp + (size_t)bh * 131072 + lane * 8;
  const unsigned short* Vg = Vf + (size_t)bh * 131072 + lane * 8;
  const unsigned short* Mg0 = maskP + (size_t)(q0 >> 4) * 32768 + lane * 8;
  const unsigned short* Mg1 = Mg0 + 32768;

  unsigned short ov = (li == 0) ? (unsigned short)0x3F80 : (unsigned short)0;
  short8 vones = {(short)ov, (short)ov, (short)ov, (short)ov,
                  (short)ov, (short)ov, (short)ov, (short)ov};

  float4v acc[2][4];
#pragma unroll
  for (int t = 0; t < 2; ++t)
#pragma unroll
    for (int nb = 0; nb < 4; ++nb) acc[t][nb] = (float4v){0, 0, 0, 0};
  float4v accd[2] = {{0, 0, 0, 0}, {0, 0, 0, 0}};

  short8 kf[4];
#pragma unroll
  for (int i = 0; i < 4; ++i) kf[i] = *(const short8*)(Kg + i * 512);
  uint4v mc0 = *(const uint4v*)Mg0;
  uint4v mc1 = *(const uint4v*)Mg1;

  for (int step = 0; step < 64; ++step) {
    int ns = (step + 1) & 63;
    // V for current step (consumed after QK+exp — latency self-hidden)
    short8 vf[4];
#pragma unroll
    for (int i = 0; i < 4; ++i)
      vf[i] = *(const short8*)(Vg + (size_t)step * 2048 + i * 512);
    // next-step K + mask prefetch
    short8 kn[4];
#pragma unroll
    for (int i = 0; i < 4; ++i)
      kn[i] = *(const short8*)(Kg + (size_t)ns * 2048 + i * 512);
    uint4v mn0 = *(const uint4v*)(Mg0 + (size_t)ns * 512);
    uint4v mn1 = *(const uint4v*)(Mg1 + (size_t)ns * 512);

    short8 pf[2];
#pragma unroll
    for (int t = 0; t < 2; ++t) {
      uint4v pw;
#pragma unroll
      for (int sb = 0; sb < 2; ++sb) {
        float4v st = {0, 0, 0, 0};
        st = __builtin_amdgcn_mfma_f32_16x16x32_bf16(kf[sb * 2], qf[t][0], st, 0, 0, 0);
        st = __builtin_amdgcn_mfma_f32_16x16x32_bf16(kf[sb * 2 + 1], qf[t][1], st, 0, 0, 0);
#pragma unroll
        for (int hh = 0; hh < 2; ++hh) {
          unsigned int mm = (t == 0) ? mc0[sb * 2 + hh] : mc1[sb * 2 + hh];
          float p0 = __builtin_amdgcn_exp2f(st[2 * hh] * __uint_as_float(mm << 16));
          float p1 = __builtin_amdgcn_exp2f(st[2 * hh + 1] * __uint_as_float(mm & 0xffff0000u));
          pw[sb * 2 + hh] = pk2bf(p0, p1);
        }
      }
      pf[t] = *(short8*)&pw;
    }
#pragma unroll
    for (int nb = 0; nb < 4; ++nb) {
      acc[0][nb] = __builtin_amdgcn_mfma_f32_16x16x32_bf16(vf[nb], pf[0], acc[0][nb], 0, 0, 0);
      acc[1][nb] = __builtin_amdgcn_mfma_f32_16x16x32_bf16(vf[nb], pf[1], acc[1][nb], 0, 0, 0);
    }
    accd[0] = __builtin_amdgcn_mfma_f32_16x16x32_bf16(vones, pf[0], accd[0], 0, 0, 0);
    accd[1] = __builtin_amdgcn_mfma_f32_16x16x32_bf16(vones, pf[1], accd[1], 0, 0, 0);

#pragma unroll
    for (int i = 0; i < 4; ++i) kf[i] = kn[i];
    mc0 = mn0; mc1 = mn1;
  }

  // den[q=li] in lane li of accd[t][0] (row 0); epilogue O^T -> O, wave-private
  unsigned short* tr = tr_all + wv * (32 * 72);
#pragma unroll
  for (int t = 0; t < 2; ++t) {
    float den = __shfl(accd[t][0], li, 64);
    float rd = 1.0f / den;
#pragma unroll
    for (int nb = 0; nb < 4; ++nb) {
      int base = (t * 16 + li) * 72 + nb * 16 + g * 4;
      *(unsigned int*)(tr + base)     = pk2bf(acc[t][nb][0] * rd, acc[t][nb][1] * rd);
      *(unsigned int*)(tr + base + 2) = pk2bf(acc[t][nb][2] * rd, acc[t][nb][3] * rd);
    }
  }
  asm volatile("s_waitcnt lgkmcnt(0)" ::: "memory");

  int b = bh >> 4, h = bh & 15;
  int rrow = lane >> 3, part = lane & 7;
#pragma unroll
  for (int i = 0; i < 4; ++i) {
    int row = i * 8 + rrow;
    short8 o = *(const short8*)(tr + row * 72 + part * 8);
    *(short8*)(AO + ((size_t)(b * SS + q0 + row)) * EE + h * 64 + part * 8) = o;
  }
}

// ---------------------------------------------------------------------------
// Kernel 4: out = AO(4096x1024 bf16) @ Wo(fp32,[k][n]) + bo. 128m x 64n tile,
// BK=64, grid 512. Wo transposed+converted during LDS staging (no WoT pass).
// ---------------------------------------------------------------------------
__global__ __launch_bounds__(256) void out_gemm(
    const unsigned short* __restrict__ AO, const float* __restrict__ Wo,
    const float* __restrict__ bo, float* __restrict__ out)
{
  __shared__ __align__(16) unsigned short at[128 * 72];
  __shared__ __align__(16) unsigned short bt[64 * 72];
  int tid = threadIdx.x, wv = tid >> 6, lane = tid & 63;
  int li = lane & 15, g = lane >> 4;
  int m0 = (blockIdx.x >> 4) * 128;
  int n0 = (blockIdx.x & 15) * 64;
  int wm = (wv & 1) * 64, wn = (wv >> 1) * 32;

  const unsigned short* Ag = AO + (size_t)m0 * 1024;
  const float* Bg = Wo + n0;
  int srow = tid >> 3, scol = (tid & 7) * 8;
  int bkrow = tid >> 4, bch = tid & 15;

  short8 apre[4];
  float4 bpre[4];
  auto ldst = [&](int k0) {
#pragma unroll
    for (int i = 0; i < 4; ++i)
      apre[i] = *(const short8*)(Ag + (size_t)(srow + i * 32) * 1024 + k0 + scol);
#pragma unroll
    for (int i = 0; i < 4; ++i)
      bpre[i] = *(const float4*)(Bg + (size_t)(k0 + bkrow + i * 16) * 1024 + bch * 4);
  };

  float4v acc[4][2];
#pragma unroll
  for (int mt = 0; mt < 4; ++mt)
#pragma unroll
    for (int nt = 0; nt < 2; ++nt) acc[mt][nt] = (float4v){0, 0, 0, 0};

  ldst(0);
  for (int k0 = 0; k0 < 1024; k0 += 64) {
    __syncthreads();
#pragma unroll
    for (int i = 0; i < 4; ++i)
      *(short8*)(at + (srow + i * 32) * 72 + scol) = apre[i];
#pragma unroll
    for (int i = 0; i < 4; ++i) {
      int kr = bkrow + i * 16;
      float4 v = bpre[i];
      bt[(bch * 4 + 0) * 72 + kr] = f2bf(v.x);
      bt[(bch * 4 + 1) * 72 + kr] = f2bf(v.y);
      bt[(bch * 4 + 2) * 72 + kr] = f2bf(v.z);
      bt[(bch * 4 + 3) * 72 + kr] = f2bf(v.w);
    }
    int nk = (k0 + 64 < 1024) ? k0 + 64 : 0;
    ldst(nk);
    __syncthreads();
#pragma unroll
    for (int ks = 0; ks < 2; ++ks) {
      short8 afr[4], bfr[2];
#pragma unroll
      for (int mt = 0; mt < 4; ++mt)
        afr[mt] = *(const short8*)(at + (wm + mt * 16 + li) * 72 + ks * 32 + g * 8);
#pragma unroll
      for (int nt = 0; nt < 2; ++nt)
        bfr[nt] = *(const short8*)(bt + (wn + nt * 16 + li) * 72 + ks * 32 + g * 8);
#pragma unroll
      for (int mt = 0; mt < 4; ++mt)
#pragma unroll
        for (int nt = 0; nt < 2; ++nt)
          acc[mt][nt] = __builtin_amdgcn_mfma_f32_16x16x32_bf16(afr[mt], bfr[nt], acc[mt][nt], 0, 0, 0);
    }
  }
#pragma unroll
  for (int nt = 0; nt < 2; ++nt) {
    float bof = bo[n0 + wn + nt * 16 + li];
#pragma unroll
    for (int mt = 0; mt < 4; ++mt)
#pragma unroll
      for (int r = 0; r < 4; ++r)
        out[(size_t)(m0 + wm + mt * 16 + g * 4 + r) * 1024 + n0 + wn + nt * 16 + li] =
            acc[mt][nt][r] + bof;
  }
}

// ---------------------------------------------------------------------------
extern "C" void kernel_launch(void* const* d_in, const int* in_sizes, int n_in,
                              void* d_out, int out_size, void* d_ws, size_t ws_size,
                              hipStream_t stream) {
  const float* x    = (const float*)d_in[0];
  const float* mask = (const float*)d_in[1];
  const float* Wq   = (const float*)d_in[2];
  const float* bq   = (const float*)d_in[3];
  const float* Wk   = (const float*)d_in[4];
  const float* bk   = (const float*)d_in[5];
  const float* Wv   = (const float*)d_in[6];
  const float* bv   = (const float*)d_in[7];
  const float* Wo   = (const float*)d_in[8];
  const float* bo   = (const float*)d_in[9];
  float* out = (float*)d_out;

  unsigned short* ws = (unsigned short*)d_ws;
  unsigned short* Q     = ws;
  unsigned short* Kp    = ws + 4194304;
  unsigned short* Vf    = ws + 8388608;
  unsigned short* AO    = ws + 12582912;
  unsigned short* maskP = ws + 16777216;
  unsigned short* W3T = AO;      // dead until attn writes AO

  prep_kernel<<<2051, 256, 0, stream>>>(mask, Wq, Wk, Wv, maskP, W3T);
  qkv_kernel<<<512, 256, 0, stream>>>(x, W3T, bq, bk, bv, Q, Kp, Vf);
  attn_kernel<<<512, 256, 0, stream>>>(Q, Kp, Vf, maskP, AO);
  out_gemm<<<512, 256, 0, stream>>>(AO, Wo, bo, out);
}